// Round 2
// baseline (153.593 us; speedup 1.0000x reference)
//
#include <hip/hip_runtime.h>
#include <hip/hip_bf16.h>

#define SEQ    2048
#define NHEAD  16
#define RPH    512          // rows per head = B*D
#define BM     128
#define BN     128
#define BK     64
#define NTH    256

#define WSTRIDE 2184        // elems per wrev copy; 2184 % 64 == 8 -> bank spread
#define WBASE_N 2176        // reversed-w valid extent (2048 + 128 zero pad)
#define GUARD_E 8           // zero guard below wbase (for i-8 vector reads)
#define WBASE_E GUARD_E     // wbase at elem 8
#define WCOP_E  (GUARD_E + 2208)        // wbase region: 2048 data + 160 zero pad
#define TOT_E   (WCOP_E + 8 * WSTRIDE)  // 2216 + 17472 = 19688 elems = 39376 B

typedef float  f32x4  __attribute__((ext_vector_type(4)));
typedef __bf16 bf16x8 __attribute__((ext_vector_type(8)));

__device__ __forceinline__ unsigned f2bf(float f) {
    union { __hip_bfloat16 h; unsigned short u; } cv;
    cv.h = __float2bfloat16(f);
    return (unsigned)cv.u;
}

__device__ __forceinline__ bf16x8 pack8(float4 a, float4 b) {
    union { bf16x8 v; unsigned u[4]; } r;
    r.u[0] = f2bf(a.x) | (f2bf(a.y) << 16);
    r.u[1] = f2bf(a.z) | (f2bf(a.w) << 16);
    r.u[2] = f2bf(b.x) | (f2bf(b.y) << 16);
    r.u[3] = f2bf(b.z) | (f2bf(b.w) << 16);
    return r.v;
}

__global__ __launch_bounds__(NTH, 3) void mixer_kernel(
    const float* __restrict__ x, const float* __restrict__ wgt,
    const float* __restrict__ bias, float* __restrict__ out)
{
    __shared__ unsigned short smem[TOT_E] __attribute__((aligned(16)));

    const int tid  = threadIdx.x;
    const int lane = tid & 63;
    const int wv   = tid >> 6;

    // ---- block decode: XCD-affine heads, heavy (big-K) col tiles first ----
    const int bid  = blockIdx.x;              // 0..1023
    const int rest = bid >> 3;                // 0..127
    const int m    = (bid & 7) + 8 * (rest & 1);
    const int r2   = rest >> 1;               // 0..63
    const int rt   = r2 & 3;                  // row tile 0..3
    const int ct   = 15 - (r2 >> 2);          // col tile, heavy first
    const int t0   = ct * BN;
    const int nch  = 2 * (ct + 1);            // K chunks of 64: s < t0+128 (even)

    const float* Xb = x   + (size_t)(m * RPH + rt * BM) * SEQ;
    float*       Ob = out + (size_t)(m * RPH + rt * BM) * SEQ;
    const float* wr = wgt  + m * SEQ;
    const float* br = bias + m * SEQ;

    // ---- phase 1: reversed bf16 weights: wbase[i] = bf16(w[2047-i]) ----
    {
        const int t8 = tid * 8;               // 0..2040
        const float* g = wr + (2040 - t8);
        float4 lo = *(const float4*)g;        // w[2040-t8 .. 2043-t8]
        float4 hi = *(const float4*)(g + 4);  // w[2044-t8 .. 2047-t8]
        uint4 v;
        v.x = f2bf(hi.w) | (f2bf(hi.z) << 16);
        v.y = f2bf(hi.y) | (f2bf(hi.x) << 16);
        v.z = f2bf(lo.w) | (f2bf(lo.z) << 16);
        v.w = f2bf(lo.y) | (f2bf(lo.x) << 16);
        *(uint4*)(smem + WBASE_E + t8) = v;
        if (tid < 21) {                       // zero guard (8) + pad (160)
            uint4 z = {0u, 0u, 0u, 0u};
            unsigned short* dst = (tid == 0) ? smem
                                 : smem + WBASE_E + 2048 + (tid - 1) * 8;
            *(uint4*)dst = z;
        }
    }
    __syncthreads();

    // ---- phase 2: 8 shifted copies, vectorized: copy_c[i] = wbase[i-c] ----
    #pragma unroll
    for (int c = 0; c < 8; ++c) {
        for (int grp = tid; grp < WSTRIDE / 8; grp += NTH) {
            const int i = grp * 8;
            uint4 g0 = *(const uint4*)(smem + WBASE_E + i - 8);
            uint4 g1 = *(const uint4*)(smem + WBASE_E + i);
            unsigned d[9] = {g0.x, g0.y, g0.z, g0.w,
                             g1.x, g1.y, g1.z, g1.w, 0u};
            const int qd = (16 - 2 * c) >> 2;
            uint4 o;
            if (c & 1) {
                o.x = (d[qd]     >> 16) | (d[qd + 1] << 16);
                o.y = (d[qd + 1] >> 16) | (d[qd + 2] << 16);
                o.z = (d[qd + 2] >> 16) | (d[qd + 3] << 16);
                o.w = (d[qd + 3] >> 16) | (d[qd + 4] << 16);
            } else {
                o.x = d[qd];     o.y = d[qd + 1];
                o.z = d[qd + 2]; o.w = d[qd + 3];
            }
            *(uint4*)(smem + WCOP_E + c * WSTRIDE + i) = o;
        }
    }
    __syncthreads();
    // wcop is read-only from here on: the K loop below has NO barriers.

    // ---- per-lane constants ----
    const int col_low = lane & 15;
    const int kq      = lane >> 4;
    const int rbase   = (wv & 1) * 64;
    const int cbase   = (wv >> 1) * 64;
    const int cpy     = (col_low + 1) & 7;    // alignment class -> copy id
    // B elem index = Bc0 + s0 + 32*ks - 16*c ; 8-aligned, in [0, 8*WSTRIDE)
    const int Bc0 = cpy * WSTRIDE + cpy + 2047 - col_low + 8 * kq - t0 - cbase;
    const unsigned short* bp = smem + WCOP_E + Bc0 - 48;  // offsets >= 0

    // A-fragment row pointers: lane reads 8 k-consecutive fp32 of one row
    const float* pr0 = Xb + (size_t)(rbase + col_low) * SEQ + 8 * kq;
    const float* pr1 = pr0 + 16 * (size_t)SEQ;
    const float* pr2 = pr0 + 32 * (size_t)SEQ;
    const float* pr3 = pr0 + 48 * (size_t)SEQ;

    f32x4 acc[4][4] = {};

    #pragma unroll 2
    for (int ch = 0; ch < nch; ++ch) {
        #pragma unroll
        for (int ks = 0; ks < 2; ++ks) {
            float4 u0 = *(const float4*)(pr0 + 32 * ks);
            float4 v0 = *(const float4*)(pr0 + 32 * ks + 4);
            float4 u1 = *(const float4*)(pr1 + 32 * ks);
            float4 v1 = *(const float4*)(pr1 + 32 * ks + 4);
            float4 u2 = *(const float4*)(pr2 + 32 * ks);
            float4 v2 = *(const float4*)(pr2 + 32 * ks + 4);
            float4 u3 = *(const float4*)(pr3 + 32 * ks);
            float4 v3 = *(const float4*)(pr3 + 32 * ks + 4);

            bf16x8 bfr[4];
            #pragma unroll
            for (int c = 0; c < 4; ++c)
                bfr[c] = *(const bf16x8*)(bp + 48 + 32 * ks - 16 * c);

            bf16x8 af[4];
            af[0] = pack8(u0, v0);
            af[1] = pack8(u1, v1);
            af[2] = pack8(u2, v2);
            af[3] = pack8(u3, v3);

            #pragma unroll
            for (int a = 0; a < 4; ++a)
                #pragma unroll
                for (int c = 0; c < 4; ++c)
                    acc[a][c] = __builtin_amdgcn_mfma_f32_16x16x32_bf16(
                                    af[a], bfr[c], acc[a][c], 0, 0, 0);
        }
        pr0 += BK; pr1 += BK; pr2 += BK; pr3 += BK;
        bp  += BK;
    }

    // ---- epilogue: C/D layout col=lane&15, row=(lane>>4)*4+reg ----
    #pragma unroll
    for (int c = 0; c < 4; ++c) {
        const int colg = t0 + cbase + 16 * c + col_low;
        const float bv = br[colg];
        #pragma unroll
        for (int a = 0; a < 4; ++a) {
            const int rowl = rbase + a * 16 + kq * 4;
            #pragma unroll
            for (int r = 0; r < 4; ++r)
                Ob[(size_t)(rowl + r) * SEQ + colg] = acc[a][c][r] + bv;
        }
    }
}

extern "C" void kernel_launch(void* const* d_in, const int* in_sizes, int n_in,
                              void* d_out, int out_size, void* d_ws, size_t ws_size,
                              hipStream_t stream) {
    const float* x  = (const float*)d_in[0];
    const float* w  = (const float*)d_in[1];
    const float* bs = (const float*)d_in[2];
    float* out = (float*)d_out;
    dim3 grid(NHEAD * 4 * 16);   // 16 heads x 4 row tiles x 16 col tiles = 1024
    dim3 block(NTH);
    hipLaunchKernelGGL(mixer_kernel, grid, block, 0, stream, x, w, bs, out);
}

// Round 3
// 52.728 us; speedup vs baseline: 2.9129x; 2.9129x over previous
//
#include <hip/hip_runtime.h>
#include <hip/hip_bf16.h>

#define SEQ    2048
#define NHEAD  16
#define RPH    512          // rows per head = B*D
#define BM     128
#define BN     128
#define BK     64
#define NTH    256

#define WSTRIDE 2184        // elems per wrev copy; 2184 % 64 == 8 -> bank spread
#define ABUF_E  8192        // elems per A buffer (128 rows x 64 cols bf16)
#define WCOP_E  (2 * ABUF_E)               // wcop after the two A buffers
#define TOT_E   (WCOP_E + 8 * WSTRIDE)     // 16384 + 17472 = 33856 elems (67712 B)
// wbase staging (guard 0..7, data 8..2055, zero pad 2056..2215) aliases abuf0

typedef float  f32x4  __attribute__((ext_vector_type(4)));
typedef __bf16 bf16x8 __attribute__((ext_vector_type(8)));

struct PF { float4 v0, v1, v2, v3, v4, v5, v6, v7; };

__device__ __forceinline__ unsigned f2bf(float f) {
    union { __hip_bfloat16 h; unsigned short u; } cv;
    cv.h = __float2bfloat16(f);
    return (unsigned)cv.u;
}

__device__ __forceinline__ uint4 pack8u(float4 a, float4 b) {
    union { bf16x8 v; uint4 u; } r;
    r.v[0] = (__bf16)a.x; r.v[1] = (__bf16)a.y;
    r.v[2] = (__bf16)a.z; r.v[3] = (__bf16)a.w;
    r.v[4] = (__bf16)b.x; r.v[5] = (__bf16)b.y;
    r.v[6] = (__bf16)b.z; r.v[7] = (__bf16)b.w;
    return r.u;
}

#define MFMA16(a, b, c) __builtin_amdgcn_mfma_f32_16x16x32_bf16((a), (b), (c), 0, 0, 0)

// One K-chunk body: load chunk CH+2 -> PFL, write chunk CH+1 (PFW) -> ABN,
// MFMA chunk CH from ABC, then lgkm-only barrier (global loads stay in flight).
#define BODY(ABC, ABN, PFW, PFL, CH)                                          \
  {                                                                           \
    const int s0_ = (CH) * BK;                                                \
    if ((CH) + 2 < nch) {                                                     \
      const float* g_ = Xb + (size_t)srow * SEQ + ((CH) + 2) * BK + scol;     \
      PFL.v0 = *(const float4*)g_;                                            \
      PFL.v1 = *(const float4*)(g_ + 4);                                      \
      PFL.v2 = *(const float4*)(g_ + 32 * SEQ);                               \
      PFL.v3 = *(const float4*)(g_ + 32 * SEQ + 4);                           \
      PFL.v4 = *(const float4*)(g_ + 64 * SEQ);                               \
      PFL.v5 = *(const float4*)(g_ + 64 * SEQ + 4);                           \
      PFL.v6 = *(const float4*)(g_ + 96 * SEQ);                               \
      PFL.v7 = *(const float4*)(g_ + 96 * SEQ + 4);                           \
    }                                                                         \
    if ((CH) + 1 < nch) {                                                     \
      *(uint4*)((ABN) + wb0) = pack8u(PFW.v0, PFW.v1);                        \
      *(uint4*)((ABN) + wb1) = pack8u(PFW.v2, PFW.v3);                        \
      *(uint4*)((ABN) + wb2) = pack8u(PFW.v4, PFW.v5);                        \
      *(uint4*)((ABN) + wb3) = pack8u(PFW.v6, PFW.v7);                        \
    }                                                                         \
    _Pragma("unroll")                                                         \
    for (int ks = 0; ks < 2; ++ks) {                                          \
      const int kb_ = 64 * ks + kq16;                                         \
      bf16x8 af[4], bfr[4];                                                   \
      af[0] = *(const bf16x8*)((ABC) + Arow0 + (kb_ ^ swz));                  \
      af[1] = *(const bf16x8*)((ABC) + Arow1 + (kb_ ^ swz));                  \
      af[2] = *(const bf16x8*)((ABC) + Arow2 + (kb_ ^ swz));                  \
      af[3] = *(const bf16x8*)((ABC) + Arow3 + (kb_ ^ swz));                  \
      const int eb_ = Bc0 + s0_ + 32 * ks;                                    \
      bfr[0] = *(const bf16x8*)(wc + eb_);                                    \
      bfr[1] = *(const bf16x8*)(wc + eb_ - 16);                               \
      bfr[2] = *(const bf16x8*)(wc + eb_ - 32);                               \
      bfr[3] = *(const bf16x8*)(wc + eb_ - 48);                               \
      _Pragma("unroll")                                                       \
      for (int a_ = 0; a_ < 4; ++a_)                                          \
        _Pragma("unroll")                                                     \
        for (int c_ = 0; c_ < 4; ++c_)                                        \
          acc[a_][c_] = MFMA16(af[a_], bfr[c_], acc[a_][c_]);                 \
    }                                                                         \
    asm volatile("s_waitcnt lgkmcnt(0)\n\ts_barrier" ::: "memory");           \
  }

__global__ __launch_bounds__(NTH, 2) void mixer_kernel(
    const float* __restrict__ x, const float* __restrict__ wgt,
    const float* __restrict__ bias, float* __restrict__ out)
{
    __shared__ unsigned short smem[TOT_E] __attribute__((aligned(16)));
    char* ab0 = (char*)smem;                    // A buffer 0 (bytes)
    char* ab1 = (char*)smem + ABUF_E * 2;       // A buffer 1 (bytes)
    unsigned short* wc = smem + WCOP_E;         // 8 shifted reversed-w copies

    const int tid  = threadIdx.x;
    const int lane = tid & 63;
    const int wv   = tid >> 6;

    // ---- block decode: XCD-affine heads, heavy (big-K) col tiles first ----
    const int bid  = blockIdx.x;               // 0..1023
    const int rest = bid >> 3;                 // 0..127
    const int m    = (bid & 7) + 8 * (rest & 1);
    const int r2   = rest >> 1;                // 0..63
    const int rt   = r2 & 3;                   // row tile 0..3
    const int ct   = 15 - (r2 >> 2);           // col tile, heavy first
    const int t0   = ct * BN;
    const int nch  = 2 * (ct + 1);             // K chunks of 64 (always even, >=2)

    const float* Xb = x   + (size_t)(m * RPH + rt * BM) * SEQ;
    float*       Ob = out + (size_t)(m * RPH + rt * BM) * SEQ;
    const float* wr = wgt  + m * SEQ;
    const float* br = bias + m * SEQ;

    // ---- staging thread map ----
    const int srow  = tid >> 3;                // 0..31
    const int scol  = (tid & 7) * 8;           // 0..56
    const int wbyte = (tid & 7) * 16;
    const int wsw   = wbyte ^ ((srow & 7) << 4);
    const int wb0   = (srow)      * 128 + wsw;
    const int wb1   = (srow + 32) * 128 + wsw;
    const int wb2   = (srow + 64) * 128 + wsw;
    const int wb3   = (srow + 96) * 128 + wsw;

    // ---- issue chunk-0/1 prefetch immediately (hides under prologue) ----
    PF pfA, pfB;
    {
        const float* g = Xb + (size_t)srow * SEQ + scol;
        pfA.v0 = *(const float4*)g;
        pfA.v1 = *(const float4*)(g + 4);
        pfA.v2 = *(const float4*)(g + 32 * SEQ);
        pfA.v3 = *(const float4*)(g + 32 * SEQ + 4);
        pfA.v4 = *(const float4*)(g + 64 * SEQ);
        pfA.v5 = *(const float4*)(g + 64 * SEQ + 4);
        pfA.v6 = *(const float4*)(g + 96 * SEQ);
        pfA.v7 = *(const float4*)(g + 96 * SEQ + 4);
        const float* h = g + BK;
        pfB.v0 = *(const float4*)h;
        pfB.v1 = *(const float4*)(h + 4);
        pfB.v2 = *(const float4*)(h + 32 * SEQ);
        pfB.v3 = *(const float4*)(h + 32 * SEQ + 4);
        pfB.v4 = *(const float4*)(h + 64 * SEQ);
        pfB.v5 = *(const float4*)(h + 64 * SEQ + 4);
        pfB.v6 = *(const float4*)(h + 96 * SEQ);
        pfB.v7 = *(const float4*)(h + 96 * SEQ + 4);
    }

    // ---- phase 1: reversed bf16 weights into abuf0-alias:
    //      wbase[i] = bf16(w[2047-i]) at elem 8+i; guard/pad zeroed ----
    {
        const int t8 = tid * 8;                // 0..2040
        const float* g = wr + (2040 - t8);
        float4 lo = *(const float4*)g;
        float4 hi = *(const float4*)(g + 4);
        uint4 v;
        v.x = f2bf(hi.w) | (f2bf(hi.z) << 16);
        v.y = f2bf(hi.y) | (f2bf(hi.x) << 16);
        v.z = f2bf(lo.w) | (f2bf(lo.z) << 16);
        v.w = f2bf(lo.y) | (f2bf(lo.x) << 16);
        *(uint4*)(smem + 8 + t8) = v;
        if (tid < 21) {                        // guard (8) + pad (160)
            uint4 z = {0u, 0u, 0u, 0u};
            unsigned short* dst = (tid == 0) ? smem
                                 : smem + 8 + 2048 + (tid - 1) * 8;
            *(uint4*)dst = z;
        }
    }
    __syncthreads();

    // ---- phase 2: 8 shifted copies, vectorized: copy_c[i] = wbase[i-c] ----
    #pragma unroll
    for (int c = 0; c < 8; ++c) {
        for (int grp = tid; grp < WSTRIDE / 8; grp += NTH) {
            const int i = grp * 8;
            uint4 g0 = *(const uint4*)(smem + 8 + i - 8);
            uint4 g1 = *(const uint4*)(smem + 8 + i);
            unsigned d[9] = {g0.x, g0.y, g0.z, g0.w,
                             g1.x, g1.y, g1.z, g1.w, 0u};
            const int qd = (16 - 2 * c) >> 2;
            uint4 o;
            if (c & 1) {
                o.x = (d[qd]     >> 16) | (d[qd + 1] << 16);
                o.y = (d[qd + 1] >> 16) | (d[qd + 2] << 16);
                o.z = (d[qd + 2] >> 16) | (d[qd + 3] << 16);
                o.w = (d[qd + 3] >> 16) | (d[qd + 4] << 16);
            } else {
                o.x = d[qd];     o.y = d[qd + 1];
                o.z = d[qd + 2]; o.w = d[qd + 3];
            }
            *(uint4*)(wc + c * WSTRIDE + i) = o;
        }
    }
    __syncthreads();

    // ---- seed abuf0 with chunk 0, freeing pfA for chunk-2 loads ----
    *(uint4*)(ab0 + wb0) = pack8u(pfA.v0, pfA.v1);
    *(uint4*)(ab0 + wb1) = pack8u(pfA.v2, pfA.v3);
    *(uint4*)(ab0 + wb2) = pack8u(pfA.v4, pfA.v5);
    *(uint4*)(ab0 + wb3) = pack8u(pfA.v6, pfA.v7);
    __syncthreads();

    // ---- per-lane MFMA constants ----
    const int col_low = lane & 15;
    const int kq      = lane >> 4;
    const int kq16    = kq * 16;
    const int swz     = (col_low & 7) << 4;
    const int rbase   = (wv & 1) * 64;
    const int cbase   = (wv >> 1) * 64;
    const int cpy     = (col_low + 1) & 7;     // alignment class -> copy id
    const int Bc0 = cpy * WSTRIDE + cpy + 2047 - col_low + 8 * kq - t0 - cbase;
    const int Arow0 = (rbase      + col_low) * 128;
    const int Arow1 = (rbase + 16 + col_low) * 128;
    const int Arow2 = (rbase + 32 + col_low) * 128;
    const int Arow3 = (rbase + 48 + col_low) * 128;

    f32x4 acc[4][4] = {};

    // ---- main loop: 1 barrier per chunk, dbuf A, pf ping-pong ----
    for (int ch = 0; ch < nch; ch += 2) {
        BODY(ab0, ab1, pfB, pfA, ch);
        BODY(ab1, ab0, pfA, pfB, ch + 1);
    }

    // ---- epilogue: C/D layout col=lane&15, row=(lane>>4)*4+reg ----
    #pragma unroll
    for (int c = 0; c < 4; ++c) {
        const int colg = t0 + cbase + 16 * c + col_low;
        const float bv = br[colg];
        #pragma unroll
        for (int a = 0; a < 4; ++a) {
            const int rowl = rbase + a * 16 + kq * 4;
            #pragma unroll
            for (int r = 0; r < 4; ++r)
                Ob[(size_t)(rowl + r) * SEQ + colg] = acc[a][c][r] + bv;
        }
    }
}

extern "C" void kernel_launch(void* const* d_in, const int* in_sizes, int n_in,
                              void* d_out, int out_size, void* d_ws, size_t ws_size,
                              hipStream_t stream) {
    const float* x  = (const float*)d_in[0];
    const float* w  = (const float*)d_in[1];
    const float* bs = (const float*)d_in[2];
    float* out = (float*)d_out;
    dim3 grid(NHEAD * 4 * 16);   // 16 heads x 4 row tiles x 16 col tiles = 1024
    dim3 block(NTH);
    hipLaunchKernelGGL(mixer_kernel, grid, block, 0, stream, x, w, bs, out);
}

// Round 4
// 49.430 us; speedup vs baseline: 3.1073x; 1.0667x over previous
//
#include <hip/hip_runtime.h>
#include <hip/hip_bf16.h>

#define SEQ    2048
#define NHEAD  16
#define RPH    512          // rows per head = B*D
#define BM     128
#define BK     64
#define NTH    256

#define WSTRIDE 2184        // elems per wrev copy; 2184 % 64 == 8 (uniform slots)
#define ABUF_E  8192        // elems per A buffer (128 rows x 64 cols bf16)
#define WCOP_E  (2 * ABUF_E)               // wcop after the two A buffers
#define TOT_E   (WCOP_E + 8 * WSTRIDE)     // 16384 + 17472 = 33856 elems (67712 B)
// wbase staging (guard 0..7, data 8..2055, zero pad 2056..2215) aliases abuf0

typedef float  f32x4  __attribute__((ext_vector_type(4)));
typedef __bf16 bf16x8 __attribute__((ext_vector_type(8)));

struct PF { float4 v0, v1, v2, v3, v4, v5, v6, v7; };

__device__ __forceinline__ unsigned f2bf(float f) {
    union { __hip_bfloat16 h; unsigned short u; } cv;
    cv.h = __float2bfloat16(f);
    return (unsigned)cv.u;
}

__device__ __forceinline__ uint4 pack8u(float4 a, float4 b) {
    union { bf16x8 v; uint4 u; } r;
    r.v[0] = (__bf16)a.x; r.v[1] = (__bf16)a.y;
    r.v[2] = (__bf16)a.z; r.v[3] = (__bf16)a.w;
    r.v[4] = (__bf16)b.x; r.v[5] = (__bf16)b.y;
    r.v[6] = (__bf16)b.z; r.v[7] = (__bf16)b.w;
    return r.u;
}

#define MFMA16(a, b, c) __builtin_amdgcn_mfma_f32_16x16x32_bf16((a), (b), (c), 0, 0, 0)

// Load the wave-private 32x64 fp32 slice of chunk CH into P (8 float4).
#define LOADPF(P, CH)                                                         \
  { const float* g_ = Xp + (size_t)(CH) * BK;                                 \
    P.v0 = *(const float4*)g_;                                                \
    P.v1 = *(const float4*)(g_ + 4);                                          \
    P.v2 = *(const float4*)(g_ + 8 * SEQ);                                    \
    P.v3 = *(const float4*)(g_ + 8 * SEQ + 4);                                \
    P.v4 = *(const float4*)(g_ + 16 * SEQ);                                   \
    P.v5 = *(const float4*)(g_ + 16 * SEQ + 4);                               \
    P.v6 = *(const float4*)(g_ + 24 * SEQ);                                   \
    P.v7 = *(const float4*)(g_ + 24 * SEQ + 4); }

// Pack+write P into the wave-private rows of buffer AB (XOR-swizzled).
#define WRITEA(AB, P)                                                         \
  { *(uint4*)((AB) + wb0) = pack8u(P.v0, P.v1);                               \
    *(uint4*)((AB) + wb1) = pack8u(P.v2, P.v3);                               \
    *(uint4*)((AB) + wb2) = pack8u(P.v4, P.v5);                               \
    *(uint4*)((AB) + wb3) = pack8u(P.v6, P.v7); }

// One K-chunk, NO barriers: wave reads only rows it wrote itself.
#define BODY(ABC, ABN, PFW, PFL, CH)                                          \
  {                                                                           \
    if ((CH) + 2 < nch) LOADPF(PFL, (CH) + 2);                                \
    if ((CH) + 1 < nch) WRITEA(ABN, PFW);                                     \
    const int s0_ = (CH) * BK;                                                \
    __builtin_amdgcn_s_setprio(1);                                            \
    _Pragma("unroll")                                                         \
    for (int ks = 0; ks < 2; ++ks) {                                          \
      const int kb_ = (64 * ks + kq16) ^ swz;                                 \
      bf16x8 af0 = *(const bf16x8*)((ABC) + Arow0 + kb_);                     \
      bf16x8 af1 = *(const bf16x8*)((ABC) + Arow1 + kb_);                     \
      const unsigned short* bp_ = wc + (Bc0 + s0_ + 32 * ks - 112);           \
      bf16x8 bf0 = *(const bf16x8*)(bp_ + 112);                               \
      bf16x8 bf1 = *(const bf16x8*)(bp_ + 96);                                \
      bf16x8 bf2 = *(const bf16x8*)(bp_ + 80);                                \
      bf16x8 bf3 = *(const bf16x8*)(bp_ + 64);                                \
      bf16x8 bf4 = *(const bf16x8*)(bp_ + 48);                                \
      bf16x8 bf5 = *(const bf16x8*)(bp_ + 32);                                \
      bf16x8 bf6 = *(const bf16x8*)(bp_ + 16);                                \
      bf16x8 bf7 = *(const bf16x8*)(bp_);                                     \
      acc[0][0] = MFMA16(af0, bf0, acc[0][0]);                                \
      acc[1][0] = MFMA16(af1, bf0, acc[1][0]);                                \
      acc[0][1] = MFMA16(af0, bf1, acc[0][1]);                                \
      acc[1][1] = MFMA16(af1, bf1, acc[1][1]);                                \
      acc[0][2] = MFMA16(af0, bf2, acc[0][2]);                                \
      acc[1][2] = MFMA16(af1, bf2, acc[1][2]);                                \
      acc[0][3] = MFMA16(af0, bf3, acc[0][3]);                                \
      acc[1][3] = MFMA16(af1, bf3, acc[1][3]);                                \
      acc[0][4] = MFMA16(af0, bf4, acc[0][4]);                                \
      acc[1][4] = MFMA16(af1, bf4, acc[1][4]);                                \
      acc[0][5] = MFMA16(af0, bf5, acc[0][5]);                                \
      acc[1][5] = MFMA16(af1, bf5, acc[1][5]);                                \
      acc[0][6] = MFMA16(af0, bf6, acc[0][6]);                                \
      acc[1][6] = MFMA16(af1, bf6, acc[1][6]);                                \
      acc[0][7] = MFMA16(af0, bf7, acc[0][7]);                                \
      acc[1][7] = MFMA16(af1, bf7, acc[1][7]);                                \
    }                                                                         \
    __builtin_amdgcn_s_setprio(0);                                            \
  }

__global__ __launch_bounds__(NTH, 2) void mixer_kernel(
    const float* __restrict__ x, const float* __restrict__ wgt,
    const float* __restrict__ bias, float* __restrict__ out)
{
    __shared__ unsigned short smem[TOT_E] __attribute__((aligned(16)));
    char* ab0 = (char*)smem;                    // A buffer 0 (bytes)
    char* ab1 = (char*)smem + ABUF_E * 2;       // A buffer 1 (bytes)
    unsigned short* wc = smem + WCOP_E;         // 8 shifted reversed-w copies

    const int tid  = threadIdx.x;
    const int lane = tid & 63;
    const int wv   = tid >> 6;

    // ---- block decode: 512 blocks, uniform 34 chunks each ----
    // bid[3:0] spreads heads across XCDs; pair (ct_hi, ct_lo) with sum 15.
    const int bid  = blockIdx.x;               // 0..511
    const int m    = (bid & 7) + 8 * ((bid >> 3) & 1);
    const int rt   = (bid >> 4) & 3;           // row tile 0..3
    const int pr   = bid >> 6;                 // 0..7
    const int ct_hi = 15 - pr;
    const int ct_lo = pr;

    const float* Xb = x   + (size_t)(m * RPH + rt * BM) * SEQ;
    float*       Ob = out + (size_t)(m * RPH + rt * BM) * SEQ;
    const float* wr = wgt  + m * SEQ;
    const float* br = bias + m * SEQ;

    // ---- wave-private staging map: wave wv owns rows [32*wv, 32*wv+32) ----
    const int sr    = lane >> 3;               // 0..7
    const int sc    = (lane & 7) * 8;          // 0..56 (fp32 col)
    const int wsw   = ((lane & 7) * 16) ^ (sr << 4);
    const int rbw   = 32 * wv;
    const int wb0   = (rbw + sr)      * 128 + wsw;
    const int wb1   = (rbw + sr + 8)  * 128 + wsw;
    const int wb2   = (rbw + sr + 16) * 128 + wsw;
    const int wb3   = (rbw + sr + 24) * 128 + wsw;
    const float* Xp = Xb + (size_t)(rbw + sr) * SEQ + sc;

    // ---- issue chunk-0/1 prefetch immediately (hides under prologue) ----
    PF pfA, pfB;
    LOADPF(pfA, 0);
    LOADPF(pfB, 1);

    // ---- phase 1: reversed bf16 weights into abuf0-alias ----
    {
        const int t8 = tid * 8;                // 0..2040
        const float* g = wr + (2040 - t8);
        float4 lo = *(const float4*)g;
        float4 hi = *(const float4*)(g + 4);
        uint4 v;
        v.x = f2bf(hi.w) | (f2bf(hi.z) << 16);
        v.y = f2bf(hi.y) | (f2bf(hi.x) << 16);
        v.z = f2bf(lo.w) | (f2bf(lo.z) << 16);
        v.w = f2bf(lo.y) | (f2bf(lo.x) << 16);
        *(uint4*)(smem + 8 + t8) = v;
        if (tid < 21) {                        // guard (8) + pad (160)
            uint4 z = {0u, 0u, 0u, 0u};
            unsigned short* dst = (tid == 0) ? smem
                                 : smem + 8 + 2048 + (tid - 1) * 8;
            *(uint4*)dst = z;
        }
    }
    __syncthreads();

    // ---- phase 2: 8 shifted copies, vectorized: copy_c[i] = wbase[i-c] ----
    #pragma unroll
    for (int c = 0; c < 8; ++c) {
        for (int grp = tid; grp < WSTRIDE / 8; grp += NTH) {
            const int i = grp * 8;
            uint4 g0 = *(const uint4*)(smem + 8 + i - 8);
            uint4 g1 = *(const uint4*)(smem + 8 + i);
            unsigned d[9] = {g0.x, g0.y, g0.z, g0.w,
                             g1.x, g1.y, g1.z, g1.w, 0u};
            const int qd = (16 - 2 * c) >> 2;
            uint4 o;
            if (c & 1) {
                o.x = (d[qd]     >> 16) | (d[qd + 1] << 16);
                o.y = (d[qd + 1] >> 16) | (d[qd + 2] << 16);
                o.z = (d[qd + 2] >> 16) | (d[qd + 3] << 16);
                o.w = (d[qd + 3] >> 16) | (d[qd + 4] << 16);
            } else {
                o.x = d[qd];     o.y = d[qd + 1];
                o.z = d[qd + 2]; o.w = d[qd + 3];
            }
            *(uint4*)(wc + c * WSTRIDE + i) = o;
        }
    }
    __syncthreads();
    // LAST barrier in the kernel: wcop read-only, A slices wave-private.

    // ---- per-lane MFMA constants ----
    const int col_low = lane & 15;
    const int kq      = lane >> 4;
    const int kq16    = kq * 16;
    const int swz     = (col_low & 7) << 4;
    const int cpy     = (col_low + 1) & 7;     // alignment class -> copy id
    const int BcBase  = cpy * WSTRIDE + cpy + 2047 - col_low + 8 * kq;
    const int Arow0   = (rbw      + col_low) * 128;
    const int Arow1   = (rbw + 16 + col_low) * 128;

    // ---- two col tiles per block: ct_hi then ct_lo (34 chunks total) ----
    #pragma unroll
    for (int half = 0; half < 2; ++half) {
        const int ct  = half ? ct_lo : ct_hi;
        const int t0  = ct << 7;
        const int nch = 2 * (ct + 1);
        const int Bc0 = BcBase - t0;

        if (half) { LOADPF(pfA, 0); LOADPF(pfB, 1); }
        WRITEA(ab0, pfA);

        f32x4 acc[2][8] = {};
        for (int ch = 0; ch < nch; ch += 2) {
            BODY(ab0, ab1, pfB, pfA, ch);
            BODY(ab1, ab0, pfA, pfB, ch + 1);
        }

        // epilogue: C/D layout col=lane&15, row=(lane>>4)*4+reg
        #pragma unroll
        for (int c = 0; c < 8; ++c) {
            const int colg = t0 + 16 * c + col_low;
            const float bv = br[colg];
            #pragma unroll
            for (int a = 0; a < 2; ++a) {
                const int rowl = rbw + 16 * a + 4 * kq;
                #pragma unroll
                for (int r = 0; r < 4; ++r)
                    __builtin_nontemporal_store(acc[a][c][r] + bv,
                        Ob + (size_t)(rowl + r) * SEQ + colg);
            }
        }
    }
}

extern "C" void kernel_launch(void* const* d_in, const int* in_sizes, int n_in,
                              void* d_out, int out_size, void* d_ws, size_t ws_size,
                              hipStream_t stream) {
    const float* x  = (const float*)d_in[0];
    const float* w  = (const float*)d_in[1];
    const float* bs = (const float*)d_in[2];
    float* out = (float*)d_out;
    dim3 grid(512);    // 16 heads x 4 row tiles x 8 uniform ct-pairs
    dim3 block(NTH);
    hipLaunchKernelGGL(mixer_kernel, grid, block, 0, stream, x, w, bs, out);
}

// Round 5
// 46.089 us; speedup vs baseline: 3.3325x; 1.0725x over previous
//
#include <hip/hip_runtime.h>
#include <hip/hip_bf16.h>

#define SEQ    2048
#define NHEAD  16
#define RPH    512          // rows per head = B*D
#define BM     128
#define BK     64
#define NTH    256

#define WSTRIDE 2184        // elems per wrev copy; 2184 % 64 == 8 (uniform slots)
#define ABUF_E  8192        // elems per A buffer (128 rows x 64 cols bf16)
#define WCOP_E  (2 * ABUF_E)               // wcop after the two A buffers
#define TOT_E   (WCOP_E + 8 * WSTRIDE)     // 16384 + 17472 = 33856 elems (67712 B)
// wbase staging (guard 0..7, data 8..2055, zero pad 2056..2215) aliases abuf0

typedef float  f32x4  __attribute__((ext_vector_type(4)));
typedef __bf16 bf16x8 __attribute__((ext_vector_type(8)));

struct PF { float4 v0, v1, v2, v3, v4, v5, v6, v7; };

__device__ __forceinline__ unsigned f2bf(float f) {
    union { __hip_bfloat16 h; unsigned short u; } cv;
    cv.h = __float2bfloat16(f);
    return (unsigned)cv.u;
}

__device__ __forceinline__ uint4 pack8u(float4 a, float4 b) {
    union { bf16x8 v; uint4 u; } r;
    r.v[0] = (__bf16)a.x; r.v[1] = (__bf16)a.y;
    r.v[2] = (__bf16)a.z; r.v[3] = (__bf16)a.w;
    r.v[4] = (__bf16)b.x; r.v[5] = (__bf16)b.y;
    r.v[6] = (__bf16)b.z; r.v[7] = (__bf16)b.w;
    return r.u;
}

#define MFMA16(a, b, c) __builtin_amdgcn_mfma_f32_16x16x32_bf16((a), (b), (c), 0, 0, 0)

// Load the wave-private 32x64 fp32 slice of chunk CH into P (8 float4).
#define LOADPF(P, CH)                                                         \
  { const float* g_ = Xp + (size_t)(CH) * BK;                                 \
    P.v0 = *(const float4*)g_;                                                \
    P.v1 = *(const float4*)(g_ + 4);                                          \
    P.v2 = *(const float4*)(g_ + 8 * SEQ);                                    \
    P.v3 = *(const float4*)(g_ + 8 * SEQ + 4);                                \
    P.v4 = *(const float4*)(g_ + 16 * SEQ);                                   \
    P.v5 = *(const float4*)(g_ + 16 * SEQ + 4);                               \
    P.v6 = *(const float4*)(g_ + 24 * SEQ);                                   \
    P.v7 = *(const float4*)(g_ + 24 * SEQ + 4); }

// Pack+write P into the wave-private rows of buffer AB (XOR-swizzled).
#define WRITEA(AB, P)                                                         \
  { *(uint4*)((AB) + wb0) = pack8u(P.v0, P.v1);                               \
    *(uint4*)((AB) + wb1) = pack8u(P.v2, P.v3);                               \
    *(uint4*)((AB) + wb2) = pack8u(P.v4, P.v5);                               \
    *(uint4*)((AB) + wb3) = pack8u(P.v6, P.v7); }

// One k-step (K=32) of one chunk: A-frags from ABC, B-frags from the shared
// pair window bw[] at indices BASE-c (dedup identity j = 2ks - c + 4*parity).
#define KSTEP(ABC, KS, BASE)                                                  \
  { const int kb_ = (64 * (KS) + kq16) ^ swz;                                 \
    bf16x8 af0 = *(const bf16x8*)((ABC) + Arow0 + kb_);                       \
    bf16x8 af1 = *(const bf16x8*)((ABC) + Arow1 + kb_);                       \
    acc[0][0] = MFMA16(af0, bw[(BASE)    ], acc[0][0]);                       \
    acc[1][0] = MFMA16(af1, bw[(BASE)    ], acc[1][0]);                       \
    acc[0][1] = MFMA16(af0, bw[(BASE) - 1], acc[0][1]);                       \
    acc[1][1] = MFMA16(af1, bw[(BASE) - 1], acc[1][1]);                       \
    acc[0][2] = MFMA16(af0, bw[(BASE) - 2], acc[0][2]);                       \
    acc[1][2] = MFMA16(af1, bw[(BASE) - 2], acc[1][2]);                       \
    acc[0][3] = MFMA16(af0, bw[(BASE) - 3], acc[0][3]);                       \
    acc[1][3] = MFMA16(af1, bw[(BASE) - 3], acc[1][3]);                       \
    acc[0][4] = MFMA16(af0, bw[(BASE) - 4], acc[0][4]);                       \
    acc[1][4] = MFMA16(af1, bw[(BASE) - 4], acc[1][4]);                       \
    acc[0][5] = MFMA16(af0, bw[(BASE) - 5], acc[0][5]);                       \
    acc[1][5] = MFMA16(af1, bw[(BASE) - 5], acc[1][5]);                       \
    acc[0][6] = MFMA16(af0, bw[(BASE) - 6], acc[0][6]);                       \
    acc[1][6] = MFMA16(af1, bw[(BASE) - 6], acc[1][6]);                       \
    acc[0][7] = MFMA16(af0, bw[(BASE) - 7], acc[0][7]);                       \
    acc[1][7] = MFMA16(af1, bw[(BASE) - 7], acc[1][7]); }

__global__ __launch_bounds__(NTH, 2) void mixer_kernel(
    const float* __restrict__ x, const float* __restrict__ wgt,
    const float* __restrict__ bias, float* __restrict__ out)
{
    __shared__ unsigned short smem[TOT_E] __attribute__((aligned(16)));
    char* ab0 = (char*)smem;                    // A buffer 0 (bytes)
    char* ab1 = (char*)smem + ABUF_E * 2;       // A buffer 1 (bytes)
    unsigned short* wc = smem + WCOP_E;         // 8 shifted reversed-w copies

    const int tid  = threadIdx.x;
    const int lane = tid & 63;
    const int wv   = tid >> 6;

    // ---- block decode: 512 blocks, uniform 34 chunks each ----
    const int bid  = blockIdx.x;               // 0..511
    const int m    = (bid & 7) + 8 * ((bid >> 3) & 1);
    const int rt   = (bid >> 4) & 3;           // row tile 0..3
    const int pr   = bid >> 6;                 // 0..7
    const int ct_hi = 15 - pr;
    const int ct_lo = pr;

    const float* Xb = x   + (size_t)(m * RPH + rt * BM) * SEQ;
    float*       Ob = out + (size_t)(m * RPH + rt * BM) * SEQ;
    const float* wr = wgt  + m * SEQ;
    const float* br = bias + m * SEQ;

    // ---- wave-private staging map: wave wv owns rows [32*wv, 32*wv+32) ----
    const int sr    = lane >> 3;               // 0..7
    const int sc    = (lane & 7) * 8;          // 0..56 (fp32 col)
    const int wsw   = ((lane & 7) * 16) ^ (sr << 4);
    const int rbw   = 32 * wv;
    const int wb0   = (rbw + sr)      * 128 + wsw;
    const int wb1   = (rbw + sr + 8)  * 128 + wsw;
    const int wb2   = (rbw + sr + 16) * 128 + wsw;
    const int wb3   = (rbw + sr + 24) * 128 + wsw;
    const float* Xp = Xb + (size_t)(rbw + sr) * SEQ + sc;

    // ---- issue chunk-0/1 prefetch immediately (hides under prologue) ----
    PF pfA, pfB;
    LOADPF(pfA, 0);
    LOADPF(pfB, 1);

    // ---- phase 1: reversed bf16 weights into abuf0-alias ----
    {
        const int t8 = tid * 8;                // 0..2040
        const float* g = wr + (2040 - t8);
        float4 lo = *(const float4*)g;
        float4 hi = *(const float4*)(g + 4);
        uint4 v;
        v.x = f2bf(hi.w) | (f2bf(hi.z) << 16);
        v.y = f2bf(hi.y) | (f2bf(hi.x) << 16);
        v.z = f2bf(lo.w) | (f2bf(lo.z) << 16);
        v.w = f2bf(lo.y) | (f2bf(lo.x) << 16);
        *(uint4*)(smem + 8 + t8) = v;
        if (tid < 21) {                        // guard (8) + pad (160)
            uint4 z = {0u, 0u, 0u, 0u};
            unsigned short* dst = (tid == 0) ? smem
                                 : smem + 8 + 2048 + (tid - 1) * 8;
            *(uint4*)dst = z;
        }
    }
    __syncthreads();

    // ---- phase 2: 8 shifted copies, vectorized: copy_c[i] = wbase[i-c] ----
    #pragma unroll
    for (int c = 0; c < 8; ++c) {
        for (int grp = tid; grp < WSTRIDE / 8; grp += NTH) {
            const int i = grp * 8;
            uint4 g0 = *(const uint4*)(smem + 8 + i - 8);
            uint4 g1 = *(const uint4*)(smem + 8 + i);
            unsigned d[9] = {g0.x, g0.y, g0.z, g0.w,
                             g1.x, g1.y, g1.z, g1.w, 0u};
            const int qd = (16 - 2 * c) >> 2;
            uint4 o;
            if (c & 1) {
                o.x = (d[qd]     >> 16) | (d[qd + 1] << 16);
                o.y = (d[qd + 1] >> 16) | (d[qd + 2] << 16);
                o.z = (d[qd + 2] >> 16) | (d[qd + 3] << 16);
                o.w = (d[qd + 3] >> 16) | (d[qd + 4] << 16);
            } else {
                o.x = d[qd];     o.y = d[qd + 1];
                o.z = d[qd + 2]; o.w = d[qd + 3];
            }
            *(uint4*)(wc + c * WSTRIDE + i) = o;
        }
    }
    __syncthreads();
    // LAST barrier in the kernel: wcop read-only, A slices wave-private.

    // ---- per-lane MFMA constants ----
    const int col_low = lane & 15;
    const int kq      = lane >> 4;
    const int kq16    = kq * 16;
    const int swz     = (col_low & 7) << 4;
    const int cpy     = (col_low + 1) & 7;     // alignment class -> copy id
    const int BcBase  = cpy * WSTRIDE + cpy + 2047 - col_low + 8 * kq;
    const int Arow0   = (rbw      + col_low) * 128;
    const int Arow1   = (rbw + 16 + col_low) * 128;

    // ---- two col tiles per block: ct_hi then ct_lo (34 chunks total) ----
    #pragma unroll
    for (int half = 0; half < 2; ++half) {
        const int ct  = half ? ct_lo : ct_hi;
        const int t0  = ct << 7;
        const int nch = 2 * (ct + 1);
        const int Bc0 = BcBase - t0;

        if (half) { LOADPF(pfA, 0); LOADPF(pfB, 1); }
        WRITEA(ab0, pfA);

        f32x4 acc[2][8] = {};
        for (int ch = 0; ch < nch; ch += 2) {
            // shared B window for the pair: 14 distinct words (vs 32 reads)
            bf16x8 bw[14];
            const unsigned short* bpp = wc + (Bc0 + 64 * ch - 112);
            #pragma unroll
            for (int i = 0; i < 14; ++i)
                bw[i] = *(const bf16x8*)(bpp + 16 * i);

            if (ch + 2 < nch) LOADPF(pfA, ch + 2);
            WRITEA(ab1, pfB);                    // chunk ch+1 (always valid)
            __builtin_amdgcn_s_setprio(1);
            KSTEP(ab0, 0, 7);
            KSTEP(ab0, 1, 9);
            __builtin_amdgcn_s_setprio(0);

            if (ch + 3 < nch) LOADPF(pfB, ch + 3);
            if (ch + 2 < nch) WRITEA(ab0, pfA);
            __builtin_amdgcn_s_setprio(1);
            KSTEP(ab1, 0, 11);
            KSTEP(ab1, 1, 13);
            __builtin_amdgcn_s_setprio(0);
        }

        // epilogue: C/D layout col=lane&15, row=(lane>>4)*4+reg
        #pragma unroll
        for (int c = 0; c < 8; ++c) {
            const int colg = t0 + 16 * c + col_low;
            const float bv = br[colg];
            #pragma unroll
            for (int a = 0; a < 2; ++a) {
                const int rowl = rbw + 16 * a + 4 * kq;
                #pragma unroll
                for (int r = 0; r < 4; ++r)
                    Ob[(size_t)(rowl + r) * SEQ + colg] = acc[a][c][r] + bv;
            }
        }
    }
}

extern "C" void kernel_launch(void* const* d_in, const int* in_sizes, int n_in,
                              void* d_out, int out_size, void* d_ws, size_t ws_size,
                              hipStream_t stream) {
    const float* x  = (const float*)d_in[0];
    const float* w  = (const float*)d_in[1];
    const float* bs = (const float*)d_in[2];
    float* out = (float*)d_out;
    dim3 grid(512);    // 16 heads x 4 row tiles x 8 uniform ct-pairs
    dim3 block(NTH);
    hipLaunchKernelGGL(mixer_kernel, grid, block, 0, stream, x, w, bs, out);
}